// Round 1
// baseline (10473.000 us; speedup 1.0000x reference)
//
#include <hip/hip_runtime.h>

// Persistent batched-GRU kernel for MI355X (gfx950), round 10.
// r9 counters: 9.36 ms, MfmaUtil 27%, VALUBusy 51%, FETCH~0 -> compute-bound,
// gate-VALU phase and MFMA phase serialized per step. Round-10:
//  (a) VALU diet: exp2 scaling folded into weights (prep_w: W_r,W_z *= -log2e,
//      W_n *= 2*log2e) and per-lane consts; gate biases folded into MFMA acc
//      init; sigmoid = rcp(1+exp2(fma)), tanh = 1-2*rcp(1+exp2(fma));
//      h publish via v_cvt_pk_bf16_f32 pairs. ~13 VALU + 6 trans per element
//      (was ~24+6).
//  (b) overlap: K-loop split by column-tile j. Phase A = j0's 24 MFMAs;
//      phase B = j1's 24 MFMAs with j0's 4 gate elements interleaved at odd
//      ks (+ sched_group_barrier MFMA6/VALU12 hints) so gate VALU hides under
//      matrix-pipe occupancy. j1 gates are the (short) tail.
// Carried from r9: register-resident weights (48 frags / 192 VGPR), h
// double-buffer + one lgkm-only barrier/step, DPP out-reduce, transposed x
// chunks, staged out chunks.

#define B_TOTAL 16384
#define T_LEN   1024
#define M_ROWS  16
#define NBLOCKS (B_TOTAL / M_ROWS)      // 1024 blocks; ~4 sequential per CU
#define NTHREADS 512                    // 8 waves
#define LDSW    264                     // h row stride in shorts
#define TCH     32                      // t-chunk length
#define NCH     (T_LEN / TCH)           // 32
#define XSTR    20                      // x_buf t-row stride (floats)
#define OSTR    33                      // out_buf row stride (floats)

typedef short short8 __attribute__((ext_vector_type(8)));
typedef float f32x4  __attribute__((ext_vector_type(4)));

__device__ unsigned short g_wsw[196608];   // swizzled, PRE-SCALED bf16 W_hh

__device__ __forceinline__ unsigned short f2b(float f) {
  unsigned u = __builtin_bit_cast(unsigned, f);
  u += 0x7fffu + ((u >> 16) & 1u);
  return (unsigned short)(u >> 16);
}
__device__ __forceinline__ unsigned cvt_pk_bf16(float lo, float hi) {
  unsigned r;
  asm("v_cvt_pk_bf16_f32 %0, %1, %2" : "=v"(r) : "v"(lo), "v"(hi));
  return r;
}
// sum over a 16-lane DPP row; result valid in the LAST lane (r16==15)
__device__ __forceinline__ float dpp_red16(float v) {
  int x = __builtin_bit_cast(int, v);
  v += __builtin_bit_cast(float, __builtin_amdgcn_update_dpp(0, x, 0x118, 0xF, 0xF, true)); // row_shr:8
  x = __builtin_bit_cast(int, v);
  v += __builtin_bit_cast(float, __builtin_amdgcn_update_dpp(0, x, 0x114, 0xF, 0xF, true)); // row_shr:4
  x = __builtin_bit_cast(int, v);
  v += __builtin_bit_cast(float, __builtin_amdgcn_update_dpp(0, x, 0x112, 0xF, 0xF, true)); // row_shr:2
  x = __builtin_bit_cast(int, v);
  v += __builtin_bit_cast(float, __builtin_amdgcn_update_dpp(0, x, 0x111, 0xF, 0xF, true)); // row_shr:1
  return v;
}
// barrier draining LDS only (no vmcnt(0): global stores stay in flight)
__device__ __forceinline__ void barrier_lgkm() {
  asm volatile("s_waitcnt lgkmcnt(0)\n\ts_barrier" ::: "memory");
}

// Swizzle W_hh (768x256 f32 row-major) into fragment-major bf16, pre-scaled:
// rows 0..511 (r,z gates) * -log2e ; rows 512..767 (n gate) * 2*log2e.
__global__ void prep_w(const float* __restrict__ w_hh) {
  int tid  = blockIdx.x * 256 + threadIdx.x;     // 196608 total
  int e    = tid & 7;
  int lane = (tid >> 3) & 63;
  int ks   = (tid >> 9) & 7;
  int nt   = tid >> 12;
  int row  = nt * 16 + (lane & 15);
  int col  = ks * 32 + (lane >> 4) * 8 + e;
  float s  = (row < 512) ? -1.44269504f : 2.88539008f;
  g_wsw[tid] = f2b(w_hh[row * 256 + col] * s);
}

// one gate element: J=col-tile, I=row-within-quad; A0/A1/A2 = acc scalars
#define GATE_EL(J, I, A0, A1, A2)                                              \
  {                                                                            \
    float t_r = __builtin_fmaf(xv[I], swr[J], (A0));                           \
    float rg  = __builtin_amdgcn_rcpf(1.0f + __builtin_amdgcn_exp2f(t_r));     \
    float t_z = __builtin_fmaf(xv[I], swz[J], (A1));                           \
    float zg  = __builtin_amdgcn_rcpf(1.0f + __builtin_amdgcn_exp2f(t_z));     \
    float t_n = __builtin_fmaf(xv[I], swn[J], sbni[J]);                        \
    float yn  = __builtin_fmaf(rg, (A2), t_n);                                 \
    float rn  = __builtin_amdgcn_rcpf(1.0f + __builtin_amdgcn_exp2f(yn));      \
    float ng  = __builtin_fmaf(-2.0f, rn, 1.0f);                               \
    float hn  = __builtin_fmaf(zg, h_reg[J][I] - ng, ng);                      \
    h_reg[J][I] = hn;                                                          \
    vo[I] += fmaxf(hn, 0.0f) * wo[J];                                          \
  }

// publish rows (q*4+I0, q*4+I0+1) of column cc[J] as one packed bf16 pair
#define PUB_PAIR(J, I0)                                                        \
  {                                                                            \
    unsigned pk = cvt_pk_bf16(h_reg[J][I0], h_reg[J][(I0) + 1]);               \
    hwp[(q * 4 + (I0)) * LDSW + cc[J]]     = (unsigned short)pk;               \
    hwp[(q * 4 + (I0) + 1) * LDSW + cc[J]] = (unsigned short)(pk >> 16);       \
  }

__global__ __launch_bounds__(NTHREADS, 2) void gru_kernel(
    const float* __restrict__ x,
    const float* __restrict__ w_ih,
    const float* __restrict__ b_ih,
    const float* __restrict__ b_hh,
    const float* __restrict__ w_out,
    const float* __restrict__ b_out,
    float* __restrict__ out)
{
  __shared__ unsigned short h_lds[2][M_ROWS * LDSW];  // 2 x 8.25 KB
  __shared__ float x_buf[2][TCH * XSTR];              // 2 x 2.5 KB, [t][row]
  __shared__ float out_buf[2][M_ROWS * OSTR];         // 2 x 2.06 KB, [row][t]
  __shared__ float op[2][8][M_ROWS];                  // 2 x 0.5 KB

  const int tid  = threadIdx.x;
  const int w    = tid >> 6;        // wave 0..7
  const int lane = tid & 63;
  const int r16  = lane & 15;
  const int q    = lane >> 4;
  const long base = (long)blockIdx.x * M_ROWS;

  for (int i = tid; i < M_ROWS * LDSW; i += NTHREADS) h_lds[0][i] = 0;  // h0 = 0

  // ---- resident weights: 48 frags (3 gates x 2 col-tiles x 8 k-steps) ----
  short8 wr[3][2][8];
#pragma unroll
  for (int g = 0; g < 3; ++g)
#pragma unroll
    for (int j = 0; j < 2; ++j)
#pragma unroll
      for (int ks = 0; ks < 8; ++ks)
        wr[g][j][ks] = *(const short8*)&g_wsw[(((g * 16 + w * 2 + j) * 8 + ks) * 64 + lane) * 8];

  // per-lane constants for cols c(j) = w*32 + j*16 + r16, pre-scaled by the
  // exp2 factors: r,z: -log2e ; n: +2*log2e
  const float C1 = 1.44269504f;
  float swr[2], swz[2], swn[2], sbr[2], sbz[2], sbni[2], sbnh[2], wo[2];
  int cc[2];
#pragma unroll
  for (int j = 0; j < 2; ++j) {
    int c = w * 32 + j * 16 + r16;
    cc[j]   = c;
    swr[j]  = -C1 * w_ih[c];
    swz[j]  = -C1 * w_ih[256 + c];
    swn[j]  = 2.0f * C1 * w_ih[512 + c];
    sbr[j]  = -C1 * (b_ih[c] + b_hh[c]);
    sbz[j]  = -C1 * (b_ih[256 + c] + b_hh[256 + c]);
    sbni[j] = 2.0f * C1 * b_ih[512 + c];
    sbnh[j] = 2.0f * C1 * b_hh[512 + c];
    wo[j]   = w_out[c];
  }
  const float bo = b_out[0];
  const f32x4 zero4 = {0.f, 0.f, 0.f, 0.f};

  float h_reg[2][4];                // C layout: row = q*4 + i, col = cc[j]
#pragma unroll
  for (int j = 0; j < 2; ++j)
#pragma unroll
    for (int i = 0; i < 4; ++i) h_reg[j][i] = 0.0f;

  const int xr = tid >> 5;          // 0..15: staging row
  const int xt = tid & 31;          // 0..31: staging t-slot

  // prefill x chunk 0 (transposed [t][row])
  x_buf[0][xt * XSTR + xr] = x[(base + xr) * T_LEN + xt];

  barrier_lgkm();

#pragma unroll 1
  for (int t = 0; t < T_LEN; ++t) {
    const int tr = t & (TCH - 1);
    const int tc = t >> 5;
    const int xp = tc & 1;
    const int rp = t & 1;

    // ---- finalize out(t-1): op[(t-1)&1] stable since last barrier ----
    if (t > 0 && tid < M_ROWS) {
      float o = bo;
#pragma unroll
      for (int ww = 0; ww < 8; ++ww) o += op[(t - 1) & 1][ww][tid];
      out_buf[((t - 1) >> 5) & 1][tid * OSTR + ((t - 1) & 31)] = o;
    }

    const unsigned short* ar = &h_lds[rp][r16 * LDSW + q * 8];
    unsigned short* hwp = &h_lds[rp ^ 1][0];
    f32x4 xv = *(const f32x4*)&x_buf[xp][tr * XSTR + q * 4];
    f32x4 vo = zero4;

    // ---- phase A: j=0 MFMAs, acc pre-loaded with fused biases ----
    f32x4 aA0 = {sbr[0], sbr[0], sbr[0], sbr[0]};
    f32x4 aA1 = {sbz[0], sbz[0], sbz[0], sbz[0]};
    f32x4 aA2 = {sbnh[0], sbnh[0], sbnh[0], sbnh[0]};
#pragma unroll
    for (int ks = 0; ks < 8; ++ks) {
      short8 a = *(const short8*)(ar + ks * 32);
      aA0 = __builtin_amdgcn_mfma_f32_16x16x32_bf16(a, wr[0][0][ks], aA0, 0, 0, 0);
      aA1 = __builtin_amdgcn_mfma_f32_16x16x32_bf16(a, wr[1][0][ks], aA1, 0, 0, 0);
      aA2 = __builtin_amdgcn_mfma_f32_16x16x32_bf16(a, wr[2][0][ks], aA2, 0, 0, 0);
    }

    // ---- phase B: j=1 MFMAs with j=0 gate elements interleaved ----
    f32x4 aB0 = {sbr[1], sbr[1], sbr[1], sbr[1]};
    f32x4 aB1 = {sbz[1], sbz[1], sbz[1], sbz[1]};
    f32x4 aB2 = {sbnh[1], sbnh[1], sbnh[1], sbnh[1]};
#pragma unroll
    for (int ks = 0; ks < 8; ++ks) {
      short8 a = *(const short8*)(ar + ks * 32);
      aB0 = __builtin_amdgcn_mfma_f32_16x16x32_bf16(a, wr[0][1][ks], aB0, 0, 0, 0);
      aB1 = __builtin_amdgcn_mfma_f32_16x16x32_bf16(a, wr[1][1][ks], aB1, 0, 0, 0);
      aB2 = __builtin_amdgcn_mfma_f32_16x16x32_bf16(a, wr[2][1][ks], aB2, 0, 0, 0);
      if (ks == 1) {
        GATE_EL(0, 0, aA0[0], aA1[0], aA2[0]);
        __builtin_amdgcn_sched_group_barrier(0x008, 6, 0);   // 6 MFMA
        __builtin_amdgcn_sched_group_barrier(0x002, 12, 0);  // gate VALU
      }
      if (ks == 3) {
        GATE_EL(0, 1, aA0[1], aA1[1], aA2[1]);
        PUB_PAIR(0, 0);
        __builtin_amdgcn_sched_group_barrier(0x008, 6, 0);
        __builtin_amdgcn_sched_group_barrier(0x002, 12, 0);
      }
      if (ks == 5) {
        GATE_EL(0, 2, aA0[2], aA1[2], aA2[2]);
        __builtin_amdgcn_sched_group_barrier(0x008, 6, 0);
        __builtin_amdgcn_sched_group_barrier(0x002, 12, 0);
      }
      if (ks == 7) {
        GATE_EL(0, 3, aA0[3], aA1[3], aA2[3]);
        PUB_PAIR(0, 2);
        __builtin_amdgcn_sched_group_barrier(0x008, 6, 0);
        __builtin_amdgcn_sched_group_barrier(0x002, 12, 0);
      }
    }

    // ---- j=1 gate tail + publish ----
    GATE_EL(1, 0, aB0[0], aB1[0], aB2[0]);
    GATE_EL(1, 1, aB0[1], aB1[1], aB2[1]);
    PUB_PAIR(1, 0);
    GATE_EL(1, 2, aB0[2], aB1[2], aB2[2]);
    GATE_EL(1, 3, aB0[3], aB1[3], aB2[3]);
    PUB_PAIR(1, 2);

    // ---- out partial: 16-lane DPP reduce, lane 15 holds the sum ----
#pragma unroll
    for (int i = 0; i < 4; ++i) vo[i] = dpp_red16(vo[i]);
    if (r16 == 15) {
#pragma unroll
      for (int i = 0; i < 4; ++i) op[t & 1][w][q * 4 + i] = vo[i];
    }

    // ---- chunk refill/flush (once per 32 steps, at tr==1) ----
    if (tr == 1) {
      if (tc + 1 < NCH)
        x_buf[xp ^ 1][xt * XSTR + xr] = x[(base + xr) * T_LEN + (tc + 1) * TCH + xt];
      if (tc > 0)
        out[(base + xr) * T_LEN + (tc - 1) * TCH + xt] =
            out_buf[(tc - 1) & 1][xr * OSTR + xt];
    }

    barrier_lgkm();
  }

  // ---- epilogue: finalize step T-1, flush last chunk ----
  if (tid < M_ROWS) {
    float o = bo;
#pragma unroll
    for (int ww = 0; ww < 8; ++ww) o += op[(T_LEN - 1) & 1][ww][tid];
    out_buf[((T_LEN - 1) >> 5) & 1][tid * OSTR + (TCH - 1)] = o;
  }
  barrier_lgkm();
  out[(base + xr) * T_LEN + (NCH - 1) * TCH + xt] =
      out_buf[(NCH - 1) & 1][xr * OSTR + xt];
}

extern "C" void kernel_launch(void* const* d_in, const int* in_sizes, int n_in,
                              void* d_out, int out_size, void* d_ws, size_t ws_size,
                              hipStream_t stream) {
  const float* x     = (const float*)d_in[0];
  const float* w_ih  = (const float*)d_in[1];
  const float* w_hh  = (const float*)d_in[2];
  const float* b_ih  = (const float*)d_in[3];
  const float* b_hh  = (const float*)d_in[4];
  const float* w_out = (const float*)d_in[5];
  const float* b_out = (const float*)d_in[6];
  float* out = (float*)d_out;

  prep_w<<<768, 256, 0, stream>>>(w_hh);
  gru_kernel<<<NBLOCKS, NTHREADS, 0, stream>>>(x, w_ih, b_ih, b_hh, w_out, b_out, out);
}